// Round 1
// baseline (270.799 us; speedup 1.0000x reference)
//
#include <hip/hip_runtime.h>
#include <math.h>

// Model: tiny 2-token transformer, E=30, H=3, D=10, B=1e6.
// Only token 1's logits are returned => post-attention path computed for token 1 only.
// q0 never needed.

#define EPS 1e-5f

__device__ __forceinline__ float gelu_exact(float x) {
    return 0.5f * x * (1.0f + erff(x * 0.70710678118654752f));
}

// Transpose weights into d_ws as [6][30][32] floats:
//   slot 0: w_in rows  0..29 (q)  -> wtq[j][f] = w_in[f*30 + j]
//   slot 1: w_in rows 30..59 (k)  -> wtk[j][f] = w_in[(30+f)*30 + j]
//   slot 2: w_in rows 60..89 (v)  -> wtv[j][f] = w_in[(60+f)*30 + j]
//   slot 3: w_out^T, slot 4: w1^T, slot 5: w2^T
__global__ void transpose_weights(const float* __restrict__ w_in,
                                  const float* __restrict__ w_out,
                                  const float* __restrict__ w1,
                                  const float* __restrict__ w2,
                                  float* __restrict__ ws) {
    int idx = blockIdx.x * blockDim.x + threadIdx.x;
    const int TOT = 6 * 30 * 32;
    if (idx >= TOT) return;
    int m = idx / (30 * 32);
    int r = (idx / 32) % 30;   // j (column of original matrix)
    int c = idx % 32;          // f (row of original matrix), padded to 32
    float v = 0.0f;
    if (c < 30) {
        switch (m) {
            case 0: v = w_in[(0  + c) * 30 + r]; break;
            case 1: v = w_in[(30 + c) * 30 + r]; break;
            case 2: v = w_in[(60 + c) * 30 + r]; break;
            case 3: v = w_out[c * 30 + r]; break;
            case 4: v = w1[c * 30 + r]; break;
            case 5: v = w2[c * 30 + r]; break;
        }
    }
    ws[idx] = v;
}

__global__ __launch_bounds__(64) void model_kernel(
    const float* __restrict__ input,   // [B,2,5]
    const float* __restrict__ w_emb,   // [30,5]
    const float* __restrict__ b_emb,   // [30]
    const float* __restrict__ b_in,    // [90]
    const float* __restrict__ b_out,   // [30]
    const float* __restrict__ b1,      // [30]
    const float* __restrict__ b2,      // [30]
    const float* __restrict__ gamma,   // [30]
    const float* __restrict__ beta,    // [30]
    const float* __restrict__ w_o,     // [3,30]
    const float* __restrict__ b_o,     // [3]
    const float* __restrict__ wt,      // [6][30][32] transposed weights
    float* __restrict__ out,           // [B,3]
    int B)
{
    // Two per-thread LDS activation slots, stride 33 floats (bank-conflict-free).
    __shared__ float S0[64 * 33];
    __shared__ float S1[64 * 33];
    const int tid = threadIdx.x;
    const int e = blockIdx.x * 64 + tid;
    if (e >= B) return;
    const int tb = tid * 33;

    const float* __restrict__ wtq = wt;
    const float* __restrict__ wtk = wt + 30 * 32;
    const float* __restrict__ wtv = wt + 2 * 30 * 32;
    const float* __restrict__ wto = wt + 3 * 30 * 32;
    const float* __restrict__ wt1 = wt + 4 * 30 * 32;
    const float* __restrict__ wt2 = wt + 5 * 30 * 32;

    // ---- load input tokens
    float in0[5], in1[5];
    const float* ip = input + (long)e * 10;
    #pragma unroll
    for (int i = 0; i < 5; ++i) { in0[i] = ip[i]; in1[i] = ip[5 + i]; }

    // ---- P1: embed + exact GELU -> LDS (x0 -> S0, x1 -> S1)
    for (int d = 0; d < 30; ++d) {
        float b = b_emb[d];
        float a0 = b, a1 = b;
        #pragma unroll
        for (int j = 0; j < 5; ++j) {
            float w = w_emb[d * 5 + j];
            a0 = fmaf(w, in0[j], a0);
            a1 = fmaf(w, in1[j], a1);
        }
        S0[tb + d] = gelu_exact(a0);
        S1[tb + d] = gelu_exact(a1);
    }

    // ---- P2: q1 (token1), k0, k1 accumulation (90 reg accumulators)
    float q1[30], k0[30], k1[30];
    #pragma unroll
    for (int f = 0; f < 30; ++f) { q1[f] = b_in[f]; k0[f] = b_in[30 + f]; k1[f] = k0[f]; }
    for (int j = 0; j < 30; ++j) {
        float xj0 = S0[tb + j];
        float xj1 = S1[tb + j];
        const float* wq = wtq + j * 32;
        const float* wk = wtk + j * 32;
        #pragma unroll
        for (int f = 0; f < 30; ++f) {
            q1[f] = fmaf(wq[f], xj1, q1[f]);
            float wkf = wk[f];
            k0[f] = fmaf(wkf, xj0, k0[f]);
            k1[f] = fmaf(wkf, xj1, k1[f]);
        }
    }

    // ---- P3: per-head scores + softmax (token-1 query only)
    float a0c[3], a1c[3];
    #pragma unroll
    for (int h = 0; h < 3; ++h) {
        float s10 = 0.0f, s11 = 0.0f;
        #pragma unroll
        for (int d = 0; d < 10; ++d) {
            float q = q1[h * 10 + d];
            s10 = fmaf(q, k0[h * 10 + d], s10);
            s11 = fmaf(q, k1[h * 10 + d], s11);
        }
        s10 *= 0.31622776601683794f;  // 1/sqrt(10)
        s11 *= 0.31622776601683794f;
        float m = fmaxf(s10, s11);
        float e0 = __expf(s10 - m), e1 = __expf(s11 - m);
        float inv = 1.0f / (e0 + e1);
        a0c[h] = e0 * inv;
        a1c[h] = e1 * inv;
    }

    // ---- P4: v0, v1 + ctx -> S0 (x0 dead after this loop)
    float v0[30], v1[30];
    #pragma unroll
    for (int f = 0; f < 30; ++f) { v0[f] = b_in[60 + f]; v1[f] = v0[f]; }
    for (int j = 0; j < 30; ++j) {
        float xj0 = S0[tb + j];
        float xj1 = S1[tb + j];
        const float* wv = wtv + j * 32;
        #pragma unroll
        for (int f = 0; f < 30; ++f) {
            float w = wv[f];
            v0[f] = fmaf(w, xj0, v0[f]);
            v1[f] = fmaf(w, xj1, v1[f]);
        }
    }
    #pragma unroll
    for (int f = 0; f < 30; ++f) {
        const int h = f / 10;  // compile-time per unrolled f
        S0[tb + f] = a0c[h] * v0[f] + a1c[h] * v1[f];  // ctx (token 1)
    }

    // ---- P5: attn_out + residual(x1) + LayerNorm -> y (regs + S1)
    float t[30];
    #pragma unroll
    for (int f = 0; f < 30; ++f) t[f] = b_out[f];
    for (int j = 0; j < 30; ++j) {
        float cj = S0[tb + j];
        const float* w = wto + j * 32;
        #pragma unroll
        for (int f = 0; f < 30; ++f) t[f] = fmaf(w[f], cj, t[f]);
    }
    float mu = 0.0f;
    #pragma unroll
    for (int f = 0; f < 30; ++f) { t[f] += S1[tb + f]; mu += t[f]; }
    mu *= (1.0f / 30.0f);
    float var = 0.0f;
    #pragma unroll
    for (int f = 0; f < 30; ++f) { float d = t[f] - mu; var = fmaf(d, d, var); }
    float rs = rsqrtf(var * (1.0f / 30.0f) + EPS);
    float y[30];
    #pragma unroll
    for (int f = 0; f < 30; ++f) {
        y[f] = (t[f] - mu) * rs * gamma[f] + beta[f];
        S1[tb + f] = y[f];   // y replaces x1
    }

    // ---- P6: FFN layer 1 + exact GELU -> S0 (h replaces ctx)
    #pragma unroll
    for (int f = 0; f < 30; ++f) t[f] = b1[f];
    for (int j = 0; j < 30; ++j) {
        float yj = S1[tb + j];
        const float* w = wt1 + j * 32;
        #pragma unroll
        for (int f = 0; f < 30; ++f) t[f] = fmaf(w[f], yj, t[f]);
    }
    #pragma unroll
    for (int f = 0; f < 30; ++f) S0[tb + f] = gelu_exact(t[f]);

    // ---- P7: FFN layer 2 + residual(y) + LayerNorm
    #pragma unroll
    for (int f = 0; f < 30; ++f) t[f] = b2[f];
    for (int j = 0; j < 30; ++j) {
        float hj = S0[tb + j];
        const float* w = wt2 + j * 32;
        #pragma unroll
        for (int f = 0; f < 30; ++f) t[f] = fmaf(w[f], hj, t[f]);
    }
    mu = 0.0f;
    #pragma unroll
    for (int f = 0; f < 30; ++f) { t[f] += y[f]; mu += t[f]; }
    mu *= (1.0f / 30.0f);
    var = 0.0f;
    #pragma unroll
    for (int f = 0; f < 30; ++f) { float d = t[f] - mu; var = fmaf(d, d, var); }
    rs = rsqrtf(var * (1.0f / 30.0f) + EPS);
    #pragma unroll
    for (int f = 0; f < 30; ++f) t[f] = (t[f] - mu) * rs * gamma[f] + beta[f];

    // ---- P8: logits for token 1
    #pragma unroll
    for (int o = 0; o < 3; ++o) {
        float a = b_o[o];
        #pragma unroll
        for (int j = 0; j < 30; ++j) a = fmaf(w_o[o * 30 + j], t[j], a);
        out[(long)e * 3 + o] = a;
    }
}

extern "C" void kernel_launch(void* const* d_in, const int* in_sizes, int n_in,
                              void* d_out, int out_size, void* d_ws, size_t ws_size,
                              hipStream_t stream) {
    const float* input = (const float*)d_in[0];
    const float* w_emb = (const float*)d_in[1];
    const float* b_emb = (const float*)d_in[2];
    const float* w_in  = (const float*)d_in[3];
    const float* b_in  = (const float*)d_in[4];
    const float* w_out = (const float*)d_in[5];
    const float* b_out = (const float*)d_in[6];
    const float* w1    = (const float*)d_in[7];
    const float* b1    = (const float*)d_in[8];
    const float* w2    = (const float*)d_in[9];
    const float* b2    = (const float*)d_in[10];
    const float* gamma = (const float*)d_in[11];
    const float* beta  = (const float*)d_in[12];
    const float* w_o   = (const float*)d_in[13];
    const float* b_o   = (const float*)d_in[14];
    float* out = (float*)d_out;
    float* wt  = (float*)d_ws;   // 6*30*32 floats = 23 KB

    const int B = in_sizes[0] / 10;

    transpose_weights<<<(6 * 30 * 32 + 255) / 256, 256, 0, stream>>>(
        w_in, w_out, w1, w2, wt);

    const int blocks = (B + 63) / 64;
    model_kernel<<<blocks, 64, 0, stream>>>(
        input, w_emb, b_emb, b_in, b_out, b1, b2, gamma, beta, w_o, b_o,
        wt, out, B);
}